// Round 3
// baseline (239.872 us; speedup 1.0000x reference)
//
#include <hip/hip_runtime.h>
#include <stdint.h>

// LIF forward recurrence:
//   mem0 = x[0]; spike0 = (mem0 > 0.5)
//   mem_t = mem_{t-1} * 0.25 * (1 - spike_{t-1}) + x_t ; spike_t = (mem_t > 0.5)
// Output: spikes [T, B, D] float32.
//
// History:
//   R2: float4, compiler pipeline -> VGPR=32, depth~1, 81 us, 2.48 TB/s.
//   R3: float2 + empty asm fences -> compiler still collapsed (VGPR=32,
//       spill traffic), narrower loads: 110 us. WORSE.
//   R4: asm-forced DEPTH=16 pipeline -> VGPR pressure >128 under
//       launch_bounds(256,4) -> buffer slots SPILLED; spill-store of an
//       in-flight asm load dest reads garbage. FAILED correctness.
//
// R5: same plan, pressure-safe and dependence-correct:
//   - DEPTH=8 (32 VGPR buffer, ~80 total: no spill possible).
//   - WAITN ties the buffer slot through the s_waitcnt asm as "+v" in/out,
//     so consumers have a true register dependence on the post-wait value
//     (rule #18: "memory" clobber alone does not order register-only VALU).
//   - Loads-only vmcnt in the loop: spikes bit-packed into 4 u32, all 32
//     nontemporal stores issued as an independent epilogue burst.

constexpr int   T_STEPS = 32;
constexpr int   DEPTH   = 8;     // float4 loads in flight per thread
constexpr float THRESH  = 0.5f;
constexpr float DECAY   = 0.25f;

typedef float v4f __attribute__((ext_vector_type(4)));

// Issue one 16B load; compiler sees an opaque asm producing buf slot.
#define ISSUE(t)                                                         \
    do {                                                                 \
        const float4* _a = xp + (size_t)(t) * (size_t)n4;                \
        asm volatile("global_load_dwordx4 %0, %1, off"                   \
                     : "=&v"(buf[(t) % DEPTH])                           \
                     : "v"(_a)                                           \
                     : "memory");                                        \
    } while (0)

// Wait until load (t) landed. At step t the oldest unconsumed load is t and
// the youngest issued is min(t+DEPTH-1, 31) -> allowed outstanding =
// min(DEPTH-1, 31-t). The buf slot is threaded through the asm ("+v") so
// every consumer depends on the post-wait value.
#define WAITN(t)                                                         \
    asm volatile("s_waitcnt vmcnt(%1)"                                   \
                 : "+v"(buf[(t) % DEPTH])                                \
                 : "n"(((DEPTH - 1) < (T_STEPS - 1 - (t)))               \
                           ? (DEPTH - 1)                                 \
                           : (T_STEPS - 1 - (t)))                        \
                 : "memory");                                            \
    __builtin_amdgcn_sched_barrier(0)

#define STEP(t)                                                          \
    do {                                                                 \
        WAITN(t);                                                        \
        v4f v = buf[(t) % DEPTH];                                        \
        if ((t) == 0) {                                                  \
            mem.x = v.x; mem.y = v.y; mem.z = v.z; mem.w = v.w;          \
        } else {                                                         \
            mem.x = mem.x * c.x + v.x;                                   \
            mem.y = mem.y * c.y + v.y;                                   \
            mem.z = mem.z * c.z + v.z;                                   \
            mem.w = mem.w * c.w + v.w;                                   \
        }                                                                \
        bool px = mem.x > THRESH;                                        \
        bool py = mem.y > THRESH;                                        \
        bool pz = mem.z > THRESH;                                        \
        bool pw = mem.w > THRESH;                                        \
        bx |= px ? (1u << (t)) : 0u;                                     \
        by |= py ? (1u << (t)) : 0u;                                     \
        bz |= pz ? (1u << (t)) : 0u;                                     \
        bw |= pw ? (1u << (t)) : 0u;                                     \
        c.x = px ? 0.0f : DECAY;                                         \
        c.y = py ? 0.0f : DECAY;                                         \
        c.z = pz ? 0.0f : DECAY;                                         \
        c.w = pw ? 0.0f : DECAY;                                         \
        if ((t) + DEPTH < T_STEPS) ISSUE((t) + DEPTH);                   \
    } while (0)

__global__ __launch_bounds__(256) void lif_fwd_kernel(
    const float4* __restrict__ x,   // [T, n4]
    float4* __restrict__ out,       // [T, n4]
    int n4)
{
    int i = blockIdx.x * 256 + threadIdx.x;
    if (i >= n4) return;

    const float4* xp = x + i;
    float4*       op = out + i;

    v4f buf[DEPTH];
    float4 mem = {0.f, 0.f, 0.f, 0.f};
    float4 c   = {DECAY, DECAY, DECAY, DECAY};
    uint32_t bx = 0, by = 0, bz = 0, bw = 0;

    // Prologue: fill the pipe with DEPTH independent loads.
    ISSUE(0); ISSUE(1); ISSUE(2); ISSUE(3);
    ISSUE(4); ISSUE(5); ISSUE(6); ISSUE(7);

    STEP(0);  STEP(1);  STEP(2);  STEP(3);
    STEP(4);  STEP(5);  STEP(6);  STEP(7);
    STEP(8);  STEP(9);  STEP(10); STEP(11);
    STEP(12); STEP(13); STEP(14); STEP(15);
    STEP(16); STEP(17); STEP(18); STEP(19);
    STEP(20); STEP(21); STEP(22); STEP(23);
    STEP(24); STEP(25); STEP(26); STEP(27);
    STEP(28); STEP(29); STEP(30); STEP(31);

    // Epilogue: unpack spike bits, burst 32 independent nt stores.
#pragma unroll
    for (int t = 0; t < T_STEPS; ++t) {
        v4f sv;
        sv.x = ((bx >> t) & 1u) ? 1.0f : 0.0f;
        sv.y = ((by >> t) & 1u) ? 1.0f : 0.0f;
        sv.z = ((bz >> t) & 1u) ? 1.0f : 0.0f;
        sv.w = ((bw >> t) & 1u) ? 1.0f : 0.0f;
        __builtin_nontemporal_store(sv, (v4f*)(op + (size_t)t * (size_t)n4));
    }
}

extern "C" void kernel_launch(void* const* d_in, const int* in_sizes, int n_in,
                              void* d_out, int out_size, void* d_ws, size_t ws_size,
                              hipStream_t stream) {
    const float* x = (const float*)d_in[0];
    float* out = (float*)d_out;

    const int total = in_sizes[0];        // T * B * D = 33_554_432
    const int n     = total / T_STEPS;    // B * D     = 1_048_576
    const int n4    = n / 4;              // 262_144 float4 work items

    const int block = 256;
    const int grid  = (n4 + block - 1) / block;  // 1024 blocks

    lif_fwd_kernel<<<grid, block, 0, stream>>>(
        reinterpret_cast<const float4*>(x),
        reinterpret_cast<float4*>(out),
        n4);
}

// Round 4
// 232.406 us; speedup vs baseline: 1.0321x; 1.0321x over previous
//
#include <hip/hip_runtime.h>
#include <stdint.h>

// LIF forward recurrence:
//   mem0 = x[0]; spike0 = (mem0 > 0.5)
//   mem_t = mem_{t-1} * 0.25 * (1 - spike_{t-1}) + x_t ; spike_t = (mem_t > 0.5)
// Output: spikes [T, B, D] float32.
//
// History:
//   R2: float4 chunked, compiler pipeline, NT stores -> 81 us, 2.48 TB/s,
//       VGPR=32, 16 waves/CU (grid cap), occupancy 35%.
//   R3: float2 + empty asm fences -> fences forced buffers live under a
//       64-VGPR cap -> scratch spills (+8MB FETCH/WRITE) -> 110 us. CONFOUNDED.
//   R4: asm-forced DEPTH=16 -> spilled in-flight asm load dests. FAILED.
//   R5: asm-forced DEPTH=8, epilogue store burst -> VGPR=72, clean traffic,
//       but 98 us / 2.0 TB/s. Forced per-wave MLP made it WORSE: the memory
//       system serves ~2-2.5 TB/s regardless of demand depth. MLP falsified.
//
// R6: the one clean untested lever is TLP. R2 structure verbatim (chunked,
// compiler-scheduled, interleaved NT stores — empirically best) at float2
// width: 524288 items -> 2048 blocks -> 8 blocks/CU -> 32 waves/CU (HW max,
// vs 16 before). No fences, no forced buffers: compiler keeps its depth-~2
// pipeline at VGPR~28, so launch_bounds(256,8) (VGPR<=64) holds full
// occupancy without spills. 8 B/lane is within the coalescing sweet spot.

constexpr int   T_STEPS = 32;
constexpr int   CHUNK   = 8;
constexpr float THRESH  = 0.5f;
constexpr float DECAY   = 0.25f;

typedef float v2f __attribute__((ext_vector_type(2)));

__device__ __forceinline__ void load_chunk(float2* buf, const float2* __restrict__ xp,
                                           int t0, int n2) {
#pragma unroll
    for (int k = 0; k < CHUNK; ++k)
        buf[k] = xp[(size_t)(t0 + k) * (size_t)n2];
}

template <int T0>
__device__ __forceinline__ void compute_chunk(const float2* buf, float2& mem, float2& s,
                                              float2* __restrict__ op, int n2) {
#pragma unroll
    for (int k = 0; k < CHUNK; ++k) {
        float2 v = buf[k];
        if (T0 + k == 0) {
            mem = v;  // mem0 = x[0]
        } else {
            // (1-s) in {0,1}; DECAY*(1-s) in {0, 0.25} exact; fma == mul+add
            // here since mem*c is exact -> bit-identical to reference.
            mem.x = mem.x * (DECAY * (1.0f - s.x)) + v.x;
            mem.y = mem.y * (DECAY * (1.0f - s.y)) + v.y;
        }
        s.x = mem.x > THRESH ? 1.0f : 0.0f;
        s.y = mem.y > THRESH ? 1.0f : 0.0f;
        v2f sv = {s.x, s.y};
        __builtin_nontemporal_store(sv, (v2f*)(op + (size_t)(T0 + k) * (size_t)n2));
    }
}

__global__ __launch_bounds__(256, 8) void lif_fwd_kernel(
    const float2* __restrict__ x,   // [T, n2]
    float2* __restrict__ out,       // [T, n2]
    int n2)
{
    int i = blockIdx.x * 256 + threadIdx.x;
    if (i >= n2) return;

    const float2* xp = x + i;
    float2*       op = out + i;

    float2 bufA[CHUNK], bufB[CHUNK];
    float2 mem, s;

    // Same schedule as the 81us float4 kernel; compiler is free to collapse
    // the buffers to its preferred pipeline depth.
    load_chunk(bufA, xp, 0, n2);
    load_chunk(bufB, xp, 8, n2);
    compute_chunk<0>(bufA, mem, s, op, n2);
    load_chunk(bufA, xp, 16, n2);
    compute_chunk<8>(bufB, mem, s, op, n2);
    load_chunk(bufB, xp, 24, n2);
    compute_chunk<16>(bufA, mem, s, op, n2);
    compute_chunk<24>(bufB, mem, s, op, n2);
}

extern "C" void kernel_launch(void* const* d_in, const int* in_sizes, int n_in,
                              void* d_out, int out_size, void* d_ws, size_t ws_size,
                              hipStream_t stream) {
    const float* x = (const float*)d_in[0];
    float* out = (float*)d_out;

    const int total = in_sizes[0];        // T * B * D = 33_554_432
    const int n     = total / T_STEPS;    // B * D     = 1_048_576
    const int n2    = n / 2;              // 524_288 float2 work items

    const int block = 256;
    const int grid  = (n2 + block - 1) / block;  // 2048 blocks -> 32 waves/CU

    lif_fwd_kernel<<<grid, block, 0, stream>>>(
        reinterpret_cast<const float2*>(x),
        reinterpret_cast<float2*>(out),
        n2);
}